// Round 10
// baseline (70.701 us; speedup 1.0000x reference)
//
#include <hip/hip_runtime.h>
#include <math.h>

// FeatureLevelAttention, algebraically collapsed.
// B=16, CIN=3, H=W=128 (HW=16384), C=256, NH=8, HD=32.
// y[b,c,p] = G[b,c] . x_p + g[b,c]; attention depends only on per-batch
// moments M=sum x x^T (3x3), s=sum x (3). Wfo=Wf@Wo folded (batch-indep).
//
// K1 k_prep  (525 blocks): moment partials | Wfo | bfo,Wb4 | aq=Wqkv@[Wi|bi]
// K2 k_final (512 blocks): prologue = attention solve (per-batch, redundant
//    per block; designated block writes att_out) + Gg fold for this block's
//    32 channels; then stream 32 ch x 4096 px (x in regs, 16 KB write runs).

#define HW 16384
#define NBATCH 16
static constexpr float SCALE_ = 0.17677669529663687f; // 32^-0.5
static constexpr float EPS_ = 1e-5f;

typedef float f32x4 __attribute__((ext_vector_type(4)));

// ws layout (floats):
//   [0, 2304)        : moment partials, 256 blocks * 9
//   [4096, 69632)    : Wfo[256][256]
//   [69632, 69888)   : bfo[256]
//   [69888, 70912)   : Wb4[256][4] = {Wi0,Wi1,Wi2,bi}
//   [71168, 74240)   : aq[768][4]
#define WS_PART 0
#define WS_WFO  4096
#define WS_BFO  69632
#define WS_WB4  69888
#define WS_AQ   71168

__device__ __forceinline__ float sigmoidf_(float z) {
  return __builtin_amdgcn_rcpf(1.0f + __expf(-z));
}

__global__ __launch_bounds__(256) void k_prep(
    const float* __restrict__ x,
    const float* __restrict__ Wi, const float* __restrict__ bi,
    const float* __restrict__ Wqkv,
    const float* __restrict__ Wo, const float* __restrict__ bo,
    const float* __restrict__ Wf, const float* __restrict__ bf,
    float* __restrict__ part, float* __restrict__ Wfo,
    float* __restrict__ bfo, float* __restrict__ Wb4,
    float* __restrict__ aqg)
{
  const int bx = blockIdx.x;
  const int tid = threadIdx.x;
  if (bx < 256) {
    // ---- per-batch moment partials ----
    const int b = bx >> 4;
    const int pi = bx & 15;
    const int p0 = pi * 1024 + tid * 4;
    const float4 a0 = *reinterpret_cast<const float4*>(x + (size_t)(b * 3 + 0) * HW + p0);
    const float4 a1 = *reinterpret_cast<const float4*>(x + (size_t)(b * 3 + 1) * HW + p0);
    const float4 a2 = *reinterpret_cast<const float4*>(x + (size_t)(b * 3 + 2) * HW + p0);
    float v[9];
    v[0] = a0.x * a0.x + a0.y * a0.y + a0.z * a0.z + a0.w * a0.w;
    v[1] = a0.x * a1.x + a0.y * a1.y + a0.z * a1.z + a0.w * a1.w;
    v[2] = a0.x * a2.x + a0.y * a2.y + a0.z * a2.z + a0.w * a2.w;
    v[3] = a1.x * a1.x + a1.y * a1.y + a1.z * a1.z + a1.w * a1.w;
    v[4] = a1.x * a2.x + a1.y * a2.y + a1.z * a2.z + a1.w * a2.w;
    v[5] = a2.x * a2.x + a2.y * a2.y + a2.z * a2.z + a2.w * a2.w;
    v[6] = a0.x + a0.y + a0.z + a0.w;
    v[7] = a1.x + a1.y + a1.z + a1.w;
    v[8] = a2.x + a2.y + a2.z + a2.w;
    __shared__ float wred[4][9];
    const int lane = tid & 63, wid = tid >> 6;
#pragma unroll
    for (int k = 0; k < 9; ++k) {
      float s = v[k];
#pragma unroll
      for (int off = 32; off; off >>= 1) s += __shfl_down(s, off, 64);
      if (lane == 0) wred[wid][k] = s;
    }
    __syncthreads();
    if (tid < 9) {
      part[bx * 9 + tid] = wred[0][tid] + wred[1][tid] + wred[2][tid] + wred[3][tid];
    }
  } else if (bx < 512) {
    // ---- Wfo = Wf @ Wo, one row per block; coalesced over i ----
    const int o = bx - 256;
    const float* wfr = Wf + (size_t)o * 256;
    const int i = tid;
    float acc = 0.f;
#pragma unroll 32
    for (int k = 0; k < 256; ++k) acc = fmaf(wfr[k], Wo[(size_t)k * 256 + i], acc);
    Wfo[(size_t)o * 256 + i] = acc;
  } else if (bx == 512) {
    // ---- Wb4 table + bfo = Wf@bo + bf ----
    Wb4[tid * 4 + 0] = Wi[tid * 3 + 0];
    Wb4[tid * 4 + 1] = Wi[tid * 3 + 1];
    Wb4[tid * 4 + 2] = Wi[tid * 3 + 2];
    Wb4[tid * 4 + 3] = bi[tid];
    float acc = bf[tid];
    const float* wfr = Wf + (size_t)tid * 256;
#pragma unroll 16
    for (int k = 0; k < 256; ++k) acc = fmaf(wfr[k], bo[k], acc);
    bfo[tid] = acc;
  } else {
    // ---- aq = Wqkv @ [Wi | bi] : 12 blocks x 64 rows, K-split by 4 ----
    const int blk = bx - 513;
    const int rl = tid >> 2;          // local row 0..63
    const int ch = tid & 3;           // K-chunk
    const int row = blk * 64 + rl;
    const float* wr = Wqkv + (size_t)row * 256 + ch * 64;
    float c0 = 0, c1 = 0, c2 = 0, c3 = 0;
#pragma unroll 8
    for (int c = 0; c < 64; ++c) {
      const float w = wr[c];
      const int cc = ch * 64 + c;
      c0 = fmaf(w, Wi[cc * 3 + 0], c0);
      c1 = fmaf(w, Wi[cc * 3 + 1], c1);
      c2 = fmaf(w, Wi[cc * 3 + 2], c2);
      c3 = fmaf(w, bi[cc], c3);
    }
    __shared__ float red[64][4][4];
    red[rl][ch][0] = c0; red[rl][ch][1] = c1;
    red[rl][ch][2] = c2; red[rl][ch][3] = c3;
    __syncthreads();
    const int j = tid & 3;
    aqg[(size_t)(blk * 64 + rl) * 4 + j] =
        red[rl][0][j] + red[rl][1][j] + red[rl][2][j] + red[rl][3][j];
  }
}

// one block per (px-chunk of 4096, c-chunk of 32, batch).
// Prologue A: attention solve for batch b (all 8 heads) -> A4vf[256][4];
//             block (x==0,y==0) also writes att_out for this batch.
// Prologue B: Gg fold for this block's 32 channels.
// Stream: x 4096 px in registers, channel-outer -> 16 KB write runs.
__global__ __launch_bounds__(256) void k_final(
    const float* __restrict__ x,
    const float* __restrict__ Wfo, const float* __restrict__ bfo,
    const float* __restrict__ aqg, const float* __restrict__ part,
    const float4* __restrict__ Wb4,
    const float* __restrict__ gamma, const float* __restrict__ beta,
    const float* __restrict__ rmean, const float* __restrict__ rvar,
    float* __restrict__ att_out, float* __restrict__ out)
{
  const int b = blockIdx.z;
  const int c0 = blockIdx.y * 32;
  const int tid = threadIdx.x;
  const bool writer = (blockIdx.x == 0) && (blockIdx.y == 0);
  __shared__ float Ms[9];
  __shared__ float aqh[96][5];
  __shared__ float att_s[32][33];
  __shared__ float A4vf[256][4];
  __shared__ float Wfo_s[32][257];   // pad: conflict-free strided reads
  __shared__ float4 partial[32][9];  // pad
  __shared__ float4 sg[32], sw[32];

  // stage Wfo slice (independent; synced by first barrier below)
#pragma unroll
  for (int it = 0; it < 8; ++it) {
    const int idx = tid + it * 256;      // 0..2047 float4s of the 32x256 slice
    const int r = idx >> 6, kq = idx & 63;
    const float4 v = *reinterpret_cast<const float4*>(
        Wfo + ((size_t)(c0 + r) * 256 + kq * 4));
    Wfo_s[r][kq * 4 + 0] = v.x; Wfo_s[r][kq * 4 + 1] = v.y;
    Wfo_s[r][kq * 4 + 2] = v.z; Wfo_s[r][kq * 4 + 3] = v.w;
  }
  if (tid < 9) {
    float s = 0.f;
    for (int j = 0; j < 16; ++j) s += part[(b * 16 + j) * 9 + tid];
    Ms[tid] = s;
  }
  __syncthreads();
  const float M00 = Ms[0], M01 = Ms[1], M02 = Ms[2], M11 = Ms[3], M12 = Ms[4], M22 = Ms[5];
  const float s0 = Ms[6], s1 = Ms[7], s2 = Ms[8];

  // ---- attention solve, head by head ----
  for (int n = 0; n < 8; ++n) {
    if (tid < 96) {
      const float4 v = *reinterpret_cast<const float4*>(aqg + (size_t)(n * 96 + tid) * 4);
      aqh[tid][0] = v.x; aqh[tid][1] = v.y; aqh[tid][2] = v.z; aqh[tid][3] = v.w;
    }
    __syncthreads();
#pragma unroll
    for (int r = 0; r < 4; ++r) {
      const int idx = tid + r * 256;
      const int d = idx >> 5, e = idx & 31;
      const float* q = aqh[d];
      const float* k = aqh[32 + e];
      const float q0 = q[0], q1 = q[1], q2 = q[2], q3 = q[3];
      const float k0 = k[0], k1 = k[1], k2 = k[2], k3 = k[3];
      const float t = q0 * (M00 * k0 + M01 * k1 + M02 * k2)
                    + q1 * (M01 * k0 + M11 * k1 + M12 * k2)
                    + q2 * (M02 * k0 + M12 * k1 + M22 * k2)
                    + q3 * (s0 * k0 + s1 * k1 + s2 * k2)
                    + k3 * (s0 * q0 + s1 * q1 + s2 * q2)
                    + 16384.0f * q3 * k3;
      const float a = sigmoidf_(SCALE_ * t);
      att_s[d][e] = a;
      if (writer) att_out[(size_t)(b * 8 + n) * 1024 + idx] = a;
    }
    __syncthreads();
    if (tid < 128) {
      const int d = tid >> 2, j = tid & 3;
      float acc = 0.f;
#pragma unroll 8
      for (int e = 0; e < 32; ++e) acc = fmaf(att_s[d][e], aqh[64 + e][j], acc);
      A4vf[n * 32 + d][j] = acc;
    }
    __syncthreads();
  }

  // ---- Gg fold for this block's 32 channels ----
  {
    const int ks = tid >> 5, o = tid & 31;   // lanes vary o -> conflict-free
    float4 acc = make_float4(0.f, 0.f, 0.f, 0.f);
#pragma unroll 8
    for (int i = 0; i < 32; ++i) {
      const float w = Wfo_s[o][ks * 32 + i];
      const float4 a = *reinterpret_cast<const float4*>(A4vf[ks * 32 + i]); // broadcast
      acc.x = fmaf(w, a.x, acc.x); acc.y = fmaf(w, a.y, acc.y);
      acc.z = fmaf(w, a.z, acc.z); acc.w = fmaf(w, a.w, acc.w);
    }
    partial[o][ks] = acc;
  }
  __syncthreads();
  if (tid < 32) {
    const int o = tid;
    float4 s = partial[o][0];
#pragma unroll
    for (int k2 = 1; k2 < 8; ++k2) {
      const float4 p = partial[o][k2];
      s.x += p.x; s.y += p.y; s.z += p.z; s.w += p.w;
    }
    const int c = c0 + o;
    const float inv = gamma[c] / sqrtf(rvar[c] + EPS_);
    const float g3 = (s.w + bfo[c] - rmean[c]) * inv + beta[c];
    sg[o] = make_float4(s.x * inv, s.y * inv, s.z * inv, g3);
    sw[o] = Wb4[c];
  }
  __syncthreads();

  // ---- stream ----
  const int pbase = blockIdx.x * 4096 + tid * 4;
  const float* xb = x + (size_t)b * 3 * HW;
  float4 X0[4], X1[4], X2[4];
#pragma unroll
  for (int pi = 0; pi < 4; ++pi) {
    const int p = pbase + pi * 1024;
    X0[pi] = *reinterpret_cast<const float4*>(xb + p);
    X1[pi] = *reinterpret_cast<const float4*>(xb + HW + p);
    X2[pi] = *reinterpret_cast<const float4*>(xb + 2 * HW + p);
  }
  float* ob = out + (size_t)(b * 256 + c0) * HW;
  for (int ci = 0; ci < 32; ++ci) {
    const float4 g = sg[ci];
    const float4 w = sw[ci];
    float* oc = ob + (size_t)ci * HW + pbase;
#pragma unroll
    for (int pi = 0; pi < 4; ++pi) {
      const float4 A = X0[pi], B = X1[pi], C = X2[pi];
      f32x4 r;
      {
        const float y = fmaf(g.x, A.x, fmaf(g.y, B.x, fmaf(g.z, C.x, g.w)));
        r.x = y * sigmoidf_(y) + fmaf(w.x, A.x, fmaf(w.y, B.x, fmaf(w.z, C.x, w.w)));
      }
      {
        const float y = fmaf(g.x, A.y, fmaf(g.y, B.y, fmaf(g.z, C.y, g.w)));
        r.y = y * sigmoidf_(y) + fmaf(w.x, A.y, fmaf(w.y, B.y, fmaf(w.z, C.y, w.w)));
      }
      {
        const float y = fmaf(g.x, A.z, fmaf(g.y, B.z, fmaf(g.z, C.z, g.w)));
        r.z = y * sigmoidf_(y) + fmaf(w.x, A.z, fmaf(w.y, B.z, fmaf(w.z, C.z, w.w)));
      }
      {
        const float y = fmaf(g.x, A.w, fmaf(g.y, B.w, fmaf(g.z, C.w, g.w)));
        r.w = y * sigmoidf_(y) + fmaf(w.x, A.w, fmaf(w.y, B.w, fmaf(w.z, C.w, w.w)));
      }
      *reinterpret_cast<f32x4*>(oc + pi * 1024) = r;
    }
  }
}

extern "C" void kernel_launch(void* const* d_in, const int* in_sizes, int n_in,
                              void* d_out, int out_size, void* d_ws, size_t ws_size,
                              hipStream_t stream) {
  const float* x     = (const float*)d_in[0];
  const float* Wi    = (const float*)d_in[1];
  const float* bi    = (const float*)d_in[2];
  const float* Wqkv  = (const float*)d_in[3];
  const float* Wo    = (const float*)d_in[4];
  const float* bo    = (const float*)d_in[5];
  const float* Wf    = (const float*)d_in[6];
  const float* bf    = (const float*)d_in[7];
  const float* gamma = (const float*)d_in[8];
  const float* beta  = (const float*)d_in[9];
  const float* rmean = (const float*)d_in[10];
  const float* rvar  = (const float*)d_in[11];

  float* out = (float*)d_out;
  float* att = out + (size_t)NBATCH * 256 * HW;
  float* wsf = (float*)d_ws;

  k_prep<<<dim3(525), dim3(256), 0, stream>>>(x, Wi, bi, Wqkv, Wo, bo, Wf, bf,
                                              wsf + WS_PART, wsf + WS_WFO,
                                              wsf + WS_BFO, wsf + WS_WB4,
                                              wsf + WS_AQ);
  k_final<<<dim3(4, 8, NBATCH), dim3(256), 0, stream>>>(
      x, wsf + WS_WFO, wsf + WS_BFO, wsf + WS_AQ, wsf + WS_PART,
      (const float4*)(wsf + WS_WB4), gamma, beta, rmean, rvar, att, out);
}

// Round 11
// 68.283 us; speedup vs baseline: 1.0354x; 1.0354x over previous
//
#include <hip/hip_runtime.h>
#include <math.h>

// FeatureLevelAttention, algebraically collapsed.
// B=16, CIN=3, H=W=128 (HW=16384), C=256, NH=8, HD=32.
// y[b,c,p] = G[b,c] . x_p + g[b,c]; attention depends only on per-batch
// moments M=sum x x^T (3x3), s=sum x (3). Wfo=Wf@Wo folded (batch-indep).
//
// K1 k_prep  (525 blocks): moment partials | Wfo | bfo,Wb4 | aq=Wqkv@[Wi|bi]
// K2 k_solveA(128 blocks): per-(b,head) attention out + A4[b][c][4]
// K3 k_final (1024 blocks): fold prologue (Gg for this block's 16 channels)
//    + stream 16 ch x 4096 px (x in regs, 16 KB contiguous write runs).

#define HW 16384
#define NBATCH 16
static constexpr float SCALE_ = 0.17677669529663687f; // 32^-0.5
static constexpr float EPS_ = 1e-5f;

typedef float f32x4 __attribute__((ext_vector_type(4)));

// ws layout (floats):
//   [0, 2304)        : moment partials, 256 blocks * 9
//   [4096, 69632)    : Wfo[256][256]
//   [69632, 69888)   : bfo[256]
//   [69888, 70912)   : Wb4[256][4] = {Wi0,Wi1,Wi2,bi}
//   [71168, 74240)   : aq[768][4]
//   [75776, 92160)   : A4g[16][256][4]
#define WS_PART 0
#define WS_WFO  4096
#define WS_BFO  69632
#define WS_WB4  69888
#define WS_AQ   71168
#define WS_A4G  75776

__device__ __forceinline__ float sigmoidf_(float z) {
  return __builtin_amdgcn_rcpf(1.0f + __expf(-z));
}

__global__ __launch_bounds__(256) void k_prep(
    const float* __restrict__ x,
    const float* __restrict__ Wi, const float* __restrict__ bi,
    const float* __restrict__ Wqkv,
    const float* __restrict__ Wo, const float* __restrict__ bo,
    const float* __restrict__ Wf, const float* __restrict__ bf,
    float* __restrict__ part, float* __restrict__ Wfo,
    float* __restrict__ bfo, float* __restrict__ Wb4,
    float* __restrict__ aqg)
{
  const int bx = blockIdx.x;
  const int tid = threadIdx.x;
  if (bx < 256) {
    // ---- per-batch moment partials ----
    const int b = bx >> 4;
    const int pi = bx & 15;
    const int p0 = pi * 1024 + tid * 4;
    const float4 a0 = *reinterpret_cast<const float4*>(x + (size_t)(b * 3 + 0) * HW + p0);
    const float4 a1 = *reinterpret_cast<const float4*>(x + (size_t)(b * 3 + 1) * HW + p0);
    const float4 a2 = *reinterpret_cast<const float4*>(x + (size_t)(b * 3 + 2) * HW + p0);
    float v[9];
    v[0] = a0.x * a0.x + a0.y * a0.y + a0.z * a0.z + a0.w * a0.w;
    v[1] = a0.x * a1.x + a0.y * a1.y + a0.z * a1.z + a0.w * a1.w;
    v[2] = a0.x * a2.x + a0.y * a2.y + a0.z * a2.z + a0.w * a2.w;
    v[3] = a1.x * a1.x + a1.y * a1.y + a1.z * a1.z + a1.w * a1.w;
    v[4] = a1.x * a2.x + a1.y * a2.y + a1.z * a2.z + a1.w * a2.w;
    v[5] = a2.x * a2.x + a2.y * a2.y + a2.z * a2.z + a2.w * a2.w;
    v[6] = a0.x + a0.y + a0.z + a0.w;
    v[7] = a1.x + a1.y + a1.z + a1.w;
    v[8] = a2.x + a2.y + a2.z + a2.w;
    __shared__ float wred[4][9];
    const int lane = tid & 63, wid = tid >> 6;
#pragma unroll
    for (int k = 0; k < 9; ++k) {
      float s = v[k];
#pragma unroll
      for (int off = 32; off; off >>= 1) s += __shfl_down(s, off, 64);
      if (lane == 0) wred[wid][k] = s;
    }
    __syncthreads();
    if (tid < 9) {
      part[bx * 9 + tid] = wred[0][tid] + wred[1][tid] + wred[2][tid] + wred[3][tid];
    }
  } else if (bx < 512) {
    // ---- Wfo = Wf @ Wo, one row per block; coalesced over i ----
    const int o = bx - 256;
    const float* wfr = Wf + (size_t)o * 256;
    const int i = tid;
    float acc = 0.f;
#pragma unroll 32
    for (int k = 0; k < 256; ++k) acc = fmaf(wfr[k], Wo[(size_t)k * 256 + i], acc);
    Wfo[(size_t)o * 256 + i] = acc;
  } else if (bx == 512) {
    // ---- Wb4 table + bfo = Wf@bo + bf ----
    Wb4[tid * 4 + 0] = Wi[tid * 3 + 0];
    Wb4[tid * 4 + 1] = Wi[tid * 3 + 1];
    Wb4[tid * 4 + 2] = Wi[tid * 3 + 2];
    Wb4[tid * 4 + 3] = bi[tid];
    float acc = bf[tid];
    const float* wfr = Wf + (size_t)tid * 256;
#pragma unroll 16
    for (int k = 0; k < 256; ++k) acc = fmaf(wfr[k], bo[k], acc);
    bfo[tid] = acc;
  } else {
    // ---- aq = Wqkv @ [Wi | bi] : 12 blocks x 64 rows, K-split by 4 ----
    const int blk = bx - 513;
    const int rl = tid >> 2;          // local row 0..63
    const int ch = tid & 3;           // K-chunk
    const int row = blk * 64 + rl;
    const float* wr = Wqkv + (size_t)row * 256 + ch * 64;
    float c0 = 0, c1 = 0, c2 = 0, c3 = 0;
#pragma unroll 8
    for (int c = 0; c < 64; ++c) {
      const float w = wr[c];
      const int cc = ch * 64 + c;
      c0 = fmaf(w, Wi[cc * 3 + 0], c0);
      c1 = fmaf(w, Wi[cc * 3 + 1], c1);
      c2 = fmaf(w, Wi[cc * 3 + 2], c2);
      c3 = fmaf(w, bi[cc], c3);
    }
    __shared__ float red[64][4][4];
    red[rl][ch][0] = c0; red[rl][ch][1] = c1;
    red[rl][ch][2] = c2; red[rl][ch][3] = c3;
    __syncthreads();
    const int j = tid & 3;
    aqg[(size_t)(blk * 64 + rl) * 4 + j] =
        red[rl][0][j] + red[rl][1][j] + red[rl][2][j] + red[rl][3][j];
  }
}

// one block per (head n, batch b): attention 32x32 + A4 head-chunk
__global__ __launch_bounds__(256) void k_solveA(
    const float* __restrict__ part, const float* __restrict__ aqg,
    float* __restrict__ att_out,   // d_out + 16*256*HW
    float* __restrict__ A4g)       // ws + WS_A4G
{
  const int n = blockIdx.x;
  const int b = blockIdx.y;
  const int tid = threadIdx.x;
  __shared__ float Ms[9];
  __shared__ float aqh[96][5];     // head rows: q 0-31, k 32-63, v 64-95
  __shared__ float att_s[32][33];
  if (tid < 9) {
    float s = 0.f;
    for (int j = 0; j < 16; ++j) s += part[(b * 16 + j) * 9 + tid];
    Ms[tid] = s;
  }
  if (tid < 96) {
    const float4 v = *reinterpret_cast<const float4*>(aqg + (size_t)(n * 96 + tid) * 4);
    aqh[tid][0] = v.x; aqh[tid][1] = v.y; aqh[tid][2] = v.z; aqh[tid][3] = v.w;
  }
  __syncthreads();
  const float M00 = Ms[0], M01 = Ms[1], M02 = Ms[2], M11 = Ms[3], M12 = Ms[4], M22 = Ms[5];
  const float s0 = Ms[6], s1 = Ms[7], s2 = Ms[8];
#pragma unroll
  for (int r = 0; r < 4; ++r) {
    const int idx = tid + r * 256;
    const int d = idx >> 5, e = idx & 31;
    const float* q = aqh[d];
    const float* k = aqh[32 + e];
    const float q0 = q[0], q1 = q[1], q2 = q[2], q3 = q[3];
    const float k0 = k[0], k1 = k[1], k2 = k[2], k3 = k[3];
    const float t = q0 * (M00 * k0 + M01 * k1 + M02 * k2)
                  + q1 * (M01 * k0 + M11 * k1 + M12 * k2)
                  + q2 * (M02 * k0 + M12 * k1 + M22 * k2)
                  + q3 * (s0 * k0 + s1 * k1 + s2 * k2)
                  + k3 * (s0 * q0 + s1 * q1 + s2 * q2)
                  + 16384.0f * q3 * k3;
    const float a = sigmoidf_(SCALE_ * t);
    att_s[d][e] = a;
    att_out[(size_t)(b * 8 + n) * 1024 + idx] = a;
  }
  __syncthreads();
  if (tid < 128) {
    const int d = tid >> 2, j = tid & 3;
    float acc = 0.f;
#pragma unroll 8
    for (int e = 0; e < 32; ++e) acc = fmaf(att_s[d][e], aqh[64 + e][j], acc);
    A4g[(size_t)(b * 256 + n * 32 + d) * 4 + j] = acc;
  }
}

// one block per (px-chunk of 4096, c-chunk of 16, batch).
// Prologue: fold Gg for this block's 16 channels (16 KB Wfo slice in LDS).
// Stream: x 4096 px in registers, channel-outer -> 16 KB write runs.
__global__ __launch_bounds__(256) void k_final(
    const float* __restrict__ x,
    const float* __restrict__ Wfo, const float* __restrict__ bfo,
    const float* __restrict__ A4g, const float4* __restrict__ Wb4,
    const float* __restrict__ gamma, const float* __restrict__ beta,
    const float* __restrict__ rmean, const float* __restrict__ rvar,
    float* __restrict__ out)
{
  const int b = blockIdx.z;
  const int c0 = blockIdx.y * 16;
  const int tid = threadIdx.x;
  __shared__ float4 A4v[256];
  __shared__ float Wfo_s[16][257];   // pad: conflict-free strided reads
  __shared__ float4 partial[16][17]; // pad
  __shared__ float4 sg[16], sw[16];

  A4v[tid] = *reinterpret_cast<const float4*>(A4g + ((size_t)b * 256 + tid) * 4);
#pragma unroll
  for (int it = 0; it < 4; ++it) {
    const int idx = tid + it * 256;      // 0..1023 float4s of the 16x256 slice
    const int r = idx >> 6, kq = idx & 63;
    const float4 v = *reinterpret_cast<const float4*>(
        Wfo + ((size_t)(c0 + r) * 256 + kq * 4));
    Wfo_s[r][kq * 4 + 0] = v.x; Wfo_s[r][kq * 4 + 1] = v.y;
    Wfo_s[r][kq * 4 + 2] = v.z; Wfo_s[r][kq * 4 + 3] = v.w;
  }
  __syncthreads();
  {
    const int ks = tid >> 4, o = tid & 15;   // lanes vary o -> conflict-light
    float4 acc = make_float4(0.f, 0.f, 0.f, 0.f);
#pragma unroll 8
    for (int i = 0; i < 16; ++i) {
      const float w = Wfo_s[o][ks * 16 + i];
      const float4 a = A4v[ks * 16 + i];   // broadcast across lanes
      acc.x = fmaf(w, a.x, acc.x); acc.y = fmaf(w, a.y, acc.y);
      acc.z = fmaf(w, a.z, acc.z); acc.w = fmaf(w, a.w, acc.w);
    }
    partial[o][ks] = acc;
  }
  __syncthreads();
  if (tid < 16) {
    const int o = tid;
    float4 s = partial[o][0];
#pragma unroll
    for (int k2 = 1; k2 < 16; ++k2) {
      const float4 p = partial[o][k2];
      s.x += p.x; s.y += p.y; s.z += p.z; s.w += p.w;
    }
    const int c = c0 + o;
    const float inv = gamma[c] / sqrtf(rvar[c] + EPS_);
    const float g3 = (s.w + bfo[c] - rmean[c]) * inv + beta[c];
    sg[o] = make_float4(s.x * inv, s.y * inv, s.z * inv, g3);
    sw[o] = Wb4[c];
  }
  __syncthreads();

  const int pbase = blockIdx.x * 4096 + tid * 4;
  const float* xb = x + (size_t)b * 3 * HW;
  float4 X0[4], X1[4], X2[4];
#pragma unroll
  for (int pi = 0; pi < 4; ++pi) {
    const int p = pbase + pi * 1024;
    X0[pi] = *reinterpret_cast<const float4*>(xb + p);
    X1[pi] = *reinterpret_cast<const float4*>(xb + HW + p);
    X2[pi] = *reinterpret_cast<const float4*>(xb + 2 * HW + p);
  }
  float* ob = out + (size_t)(b * 256 + c0) * HW;
  for (int ci = 0; ci < 16; ++ci) {
    const float4 g = sg[ci];
    const float4 w = sw[ci];
    float* oc = ob + (size_t)ci * HW + pbase;
#pragma unroll
    for (int pi = 0; pi < 4; ++pi) {
      const float4 A = X0[pi], B = X1[pi], C = X2[pi];
      f32x4 r;
      {
        const float y = fmaf(g.x, A.x, fmaf(g.y, B.x, fmaf(g.z, C.x, g.w)));
        r.x = y * sigmoidf_(y) + fmaf(w.x, A.x, fmaf(w.y, B.x, fmaf(w.z, C.x, w.w)));
      }
      {
        const float y = fmaf(g.x, A.y, fmaf(g.y, B.y, fmaf(g.z, C.y, g.w)));
        r.y = y * sigmoidf_(y) + fmaf(w.x, A.y, fmaf(w.y, B.y, fmaf(w.z, C.y, w.w)));
      }
      {
        const float y = fmaf(g.x, A.z, fmaf(g.y, B.z, fmaf(g.z, C.z, g.w)));
        r.z = y * sigmoidf_(y) + fmaf(w.x, A.z, fmaf(w.y, B.z, fmaf(w.z, C.z, w.w)));
      }
      {
        const float y = fmaf(g.x, A.w, fmaf(g.y, B.w, fmaf(g.z, C.w, g.w)));
        r.w = y * sigmoidf_(y) + fmaf(w.x, A.w, fmaf(w.y, B.w, fmaf(w.z, C.w, w.w)));
      }
      *reinterpret_cast<f32x4*>(oc + pi * 1024) = r;
    }
  }
}

extern "C" void kernel_launch(void* const* d_in, const int* in_sizes, int n_in,
                              void* d_out, int out_size, void* d_ws, size_t ws_size,
                              hipStream_t stream) {
  const float* x     = (const float*)d_in[0];
  const float* Wi    = (const float*)d_in[1];
  const float* bi    = (const float*)d_in[2];
  const float* Wqkv  = (const float*)d_in[3];
  const float* Wo    = (const float*)d_in[4];
  const float* bo    = (const float*)d_in[5];
  const float* Wf    = (const float*)d_in[6];
  const float* bf    = (const float*)d_in[7];
  const float* gamma = (const float*)d_in[8];
  const float* beta  = (const float*)d_in[9];
  const float* rmean = (const float*)d_in[10];
  const float* rvar  = (const float*)d_in[11];

  float* out = (float*)d_out;
  float* att = out + (size_t)NBATCH * 256 * HW;
  float* wsf = (float*)d_ws;

  k_prep<<<dim3(525), dim3(256), 0, stream>>>(x, Wi, bi, Wqkv, Wo, bo, Wf, bf,
                                              wsf + WS_PART, wsf + WS_WFO,
                                              wsf + WS_BFO, wsf + WS_WB4,
                                              wsf + WS_AQ);
  k_solveA<<<dim3(8, NBATCH), dim3(256), 0, stream>>>(wsf + WS_PART, wsf + WS_AQ,
                                                      att, wsf + WS_A4G);
  k_final<<<dim3(4, 16, NBATCH), dim3(256), 0, stream>>>(
      x, wsf + WS_WFO, wsf + WS_BFO, wsf + WS_A4G,
      (const float4*)(wsf + WS_WB4), gamma, beta, rmean, rvar, out);
}

// Round 12
// 64.705 us; speedup vs baseline: 1.0927x; 1.0553x over previous
//
#include <hip/hip_runtime.h>
#include <math.h>

// FeatureLevelAttention, algebraically collapsed.  (R9 configuration —
// best measured: 65.2 us. All neighboring variants regress.)
// B=16, CIN=3, H=W=128 (HW=16384), C=256, NH=8, HD=32.
// y[b,c,p] = G[b,c] . x_p + g[b,c]; attention depends only on per-batch
// moments M=sum x x^T (3x3), s=sum x (3). Wfo=Wf@Wo folded (batch-indep).
//
// K1 k_prep  (525 blocks): moment partials | Wfo | bfo,Wb4 | aq=Wqkv@[Wi|bi]
// K2 k_solveA(128 blocks): per-(b,head) attention out + A4[b][c][4]
// K3 k_final (512 blocks): fold prologue (Gg for this block's 32 channels)
//    + stream 32 ch x 4096 px (x in regs, 16 KB contiguous write runs).

#define HW 16384
#define NBATCH 16
static constexpr float SCALE_ = 0.17677669529663687f; // 32^-0.5
static constexpr float EPS_ = 1e-5f;

typedef float f32x4 __attribute__((ext_vector_type(4)));

// ws layout (floats):
//   [0, 2304)        : moment partials, 256 blocks * 9
//   [4096, 69632)    : Wfo[256][256]
//   [69632, 69888)   : bfo[256]
//   [69888, 70912)   : Wb4[256][4] = {Wi0,Wi1,Wi2,bi}
//   [71168, 74240)   : aq[768][4]
//   [75776, 92160)   : A4g[16][256][4]
#define WS_PART 0
#define WS_WFO  4096
#define WS_BFO  69632
#define WS_WB4  69888
#define WS_AQ   71168
#define WS_A4G  75776

__device__ __forceinline__ float sigmoidf_(float z) {
  return __builtin_amdgcn_rcpf(1.0f + __expf(-z));
}

__global__ __launch_bounds__(256) void k_prep(
    const float* __restrict__ x,
    const float* __restrict__ Wi, const float* __restrict__ bi,
    const float* __restrict__ Wqkv,
    const float* __restrict__ Wo, const float* __restrict__ bo,
    const float* __restrict__ Wf, const float* __restrict__ bf,
    float* __restrict__ part, float* __restrict__ Wfo,
    float* __restrict__ bfo, float* __restrict__ Wb4,
    float* __restrict__ aqg)
{
  const int bx = blockIdx.x;
  const int tid = threadIdx.x;
  if (bx < 256) {
    // ---- per-batch moment partials ----
    const int b = bx >> 4;
    const int pi = bx & 15;
    const int p0 = pi * 1024 + tid * 4;
    const float4 a0 = *reinterpret_cast<const float4*>(x + (size_t)(b * 3 + 0) * HW + p0);
    const float4 a1 = *reinterpret_cast<const float4*>(x + (size_t)(b * 3 + 1) * HW + p0);
    const float4 a2 = *reinterpret_cast<const float4*>(x + (size_t)(b * 3 + 2) * HW + p0);
    float v[9];
    v[0] = a0.x * a0.x + a0.y * a0.y + a0.z * a0.z + a0.w * a0.w;
    v[1] = a0.x * a1.x + a0.y * a1.y + a0.z * a1.z + a0.w * a1.w;
    v[2] = a0.x * a2.x + a0.y * a2.y + a0.z * a2.z + a0.w * a2.w;
    v[3] = a1.x * a1.x + a1.y * a1.y + a1.z * a1.z + a1.w * a1.w;
    v[4] = a1.x * a2.x + a1.y * a2.y + a1.z * a2.z + a1.w * a2.w;
    v[5] = a2.x * a2.x + a2.y * a2.y + a2.z * a2.z + a2.w * a2.w;
    v[6] = a0.x + a0.y + a0.z + a0.w;
    v[7] = a1.x + a1.y + a1.z + a1.w;
    v[8] = a2.x + a2.y + a2.z + a2.w;
    __shared__ float wred[4][9];
    const int lane = tid & 63, wid = tid >> 6;
#pragma unroll
    for (int k = 0; k < 9; ++k) {
      float s = v[k];
#pragma unroll
      for (int off = 32; off; off >>= 1) s += __shfl_down(s, off, 64);
      if (lane == 0) wred[wid][k] = s;
    }
    __syncthreads();
    if (tid < 9) {
      part[bx * 9 + tid] = wred[0][tid] + wred[1][tid] + wred[2][tid] + wred[3][tid];
    }
  } else if (bx < 512) {
    // ---- Wfo = Wf @ Wo, one row per block; coalesced over i ----
    const int o = bx - 256;
    const float* wfr = Wf + (size_t)o * 256;
    const int i = tid;
    float acc = 0.f;
#pragma unroll 32
    for (int k = 0; k < 256; ++k) acc = fmaf(wfr[k], Wo[(size_t)k * 256 + i], acc);
    Wfo[(size_t)o * 256 + i] = acc;
  } else if (bx == 512) {
    // ---- Wb4 table + bfo = Wf@bo + bf ----
    Wb4[tid * 4 + 0] = Wi[tid * 3 + 0];
    Wb4[tid * 4 + 1] = Wi[tid * 3 + 1];
    Wb4[tid * 4 + 2] = Wi[tid * 3 + 2];
    Wb4[tid * 4 + 3] = bi[tid];
    float acc = bf[tid];
    const float* wfr = Wf + (size_t)tid * 256;
#pragma unroll 16
    for (int k = 0; k < 256; ++k) acc = fmaf(wfr[k], bo[k], acc);
    bfo[tid] = acc;
  } else {
    // ---- aq = Wqkv @ [Wi | bi] : 12 blocks x 64 rows, K-split by 4 ----
    const int blk = bx - 513;
    const int rl = tid >> 2;          // local row 0..63
    const int ch = tid & 3;           // K-chunk
    const int row = blk * 64 + rl;
    const float* wr = Wqkv + (size_t)row * 256 + ch * 64;
    float c0 = 0, c1 = 0, c2 = 0, c3 = 0;
#pragma unroll 8
    for (int c = 0; c < 64; ++c) {
      const float w = wr[c];
      const int cc = ch * 64 + c;
      c0 = fmaf(w, Wi[cc * 3 + 0], c0);
      c1 = fmaf(w, Wi[cc * 3 + 1], c1);
      c2 = fmaf(w, Wi[cc * 3 + 2], c2);
      c3 = fmaf(w, bi[cc], c3);
    }
    __shared__ float red[64][4][4];
    red[rl][ch][0] = c0; red[rl][ch][1] = c1;
    red[rl][ch][2] = c2; red[rl][ch][3] = c3;
    __syncthreads();
    const int j = tid & 3;
    aqg[(size_t)(blk * 64 + rl) * 4 + j] =
        red[rl][0][j] + red[rl][1][j] + red[rl][2][j] + red[rl][3][j];
  }
}

// one block per (head n, batch b): attention 32x32 + A4 head-chunk
__global__ __launch_bounds__(256) void k_solveA(
    const float* __restrict__ part, const float* __restrict__ aqg,
    float* __restrict__ att_out,   // d_out + 16*256*HW
    float* __restrict__ A4g)       // ws + WS_A4G
{
  const int n = blockIdx.x;
  const int b = blockIdx.y;
  const int tid = threadIdx.x;
  __shared__ float Ms[9];
  __shared__ float aqh[96][5];     // head rows: q 0-31, k 32-63, v 64-95
  __shared__ float att_s[32][33];
  if (tid < 9) {
    float s = 0.f;
    for (int j = 0; j < 16; ++j) s += part[(b * 16 + j) * 9 + tid];
    Ms[tid] = s;
  }
  if (tid < 96) {
    const float4 v = *reinterpret_cast<const float4*>(aqg + (size_t)(n * 96 + tid) * 4);
    aqh[tid][0] = v.x; aqh[tid][1] = v.y; aqh[tid][2] = v.z; aqh[tid][3] = v.w;
  }
  __syncthreads();
  const float M00 = Ms[0], M01 = Ms[1], M02 = Ms[2], M11 = Ms[3], M12 = Ms[4], M22 = Ms[5];
  const float s0 = Ms[6], s1 = Ms[7], s2 = Ms[8];
#pragma unroll
  for (int r = 0; r < 4; ++r) {
    const int idx = tid + r * 256;
    const int d = idx >> 5, e = idx & 31;
    const float* q = aqh[d];
    const float* k = aqh[32 + e];
    const float q0 = q[0], q1 = q[1], q2 = q[2], q3 = q[3];
    const float k0 = k[0], k1 = k[1], k2 = k[2], k3 = k[3];
    const float t = q0 * (M00 * k0 + M01 * k1 + M02 * k2)
                  + q1 * (M01 * k0 + M11 * k1 + M12 * k2)
                  + q2 * (M02 * k0 + M12 * k1 + M22 * k2)
                  + q3 * (s0 * k0 + s1 * k1 + s2 * k2)
                  + k3 * (s0 * q0 + s1 * q1 + s2 * q2)
                  + 16384.0f * q3 * k3;
    const float a = sigmoidf_(SCALE_ * t);
    att_s[d][e] = a;
    att_out[(size_t)(b * 8 + n) * 1024 + idx] = a;
  }
  __syncthreads();
  if (tid < 128) {
    const int d = tid >> 2, j = tid & 3;
    float acc = 0.f;
#pragma unroll 8
    for (int e = 0; e < 32; ++e) acc = fmaf(att_s[d][e], aqh[64 + e][j], acc);
    A4g[(size_t)(b * 256 + n * 32 + d) * 4 + j] = acc;
  }
}

// one block per (px-chunk of 4096, c-chunk of 32, batch).
// Prologue: fold Gg for this block's 32 channels (Wfo slice in LDS).
// Stream: x 4096 px in registers, channel-outer -> 16 KB write runs.
__global__ __launch_bounds__(256) void k_final(
    const float* __restrict__ x,
    const float* __restrict__ Wfo, const float* __restrict__ bfo,
    const float* __restrict__ A4g, const float4* __restrict__ Wb4,
    const float* __restrict__ gamma, const float* __restrict__ beta,
    const float* __restrict__ rmean, const float* __restrict__ rvar,
    float* __restrict__ out)
{
  const int b = blockIdx.z;
  const int c0 = blockIdx.y * 32;
  const int tid = threadIdx.x;
  __shared__ float4 A4v[256];
  __shared__ float Wfo_s[32][257];   // pad: conflict-free strided reads
  __shared__ float4 partial[32][9];  // pad
  __shared__ float4 sg[32], sw[32];

  A4v[tid] = *reinterpret_cast<const float4*>(A4g + ((size_t)b * 256 + tid) * 4);
#pragma unroll
  for (int it = 0; it < 8; ++it) {
    const int idx = tid + it * 256;      // 0..2047 float4s of the 32x256 slice
    const int r = idx >> 6, kq = idx & 63;
    const float4 v = *reinterpret_cast<const float4*>(
        Wfo + ((size_t)(c0 + r) * 256 + kq * 4));
    Wfo_s[r][kq * 4 + 0] = v.x; Wfo_s[r][kq * 4 + 1] = v.y;
    Wfo_s[r][kq * 4 + 2] = v.z; Wfo_s[r][kq * 4 + 3] = v.w;
  }
  __syncthreads();
  {
    const int ks = tid >> 5, o = tid & 31;   // lanes vary o -> conflict-free
    float4 acc = make_float4(0.f, 0.f, 0.f, 0.f);
#pragma unroll 8
    for (int i = 0; i < 32; ++i) {
      const float w = Wfo_s[o][ks * 32 + i];
      const float4 a = A4v[ks * 32 + i];   // broadcast across lanes
      acc.x = fmaf(w, a.x, acc.x); acc.y = fmaf(w, a.y, acc.y);
      acc.z = fmaf(w, a.z, acc.z); acc.w = fmaf(w, a.w, acc.w);
    }
    partial[o][ks] = acc;
  }
  __syncthreads();
  if (tid < 32) {
    const int o = tid;
    float4 s = partial[o][0];
#pragma unroll
    for (int k2 = 1; k2 < 8; ++k2) {
      const float4 p = partial[o][k2];
      s.x += p.x; s.y += p.y; s.z += p.z; s.w += p.w;
    }
    const int c = c0 + o;
    const float inv = gamma[c] / sqrtf(rvar[c] + EPS_);
    const float g3 = (s.w + bfo[c] - rmean[c]) * inv + beta[c];
    sg[o] = make_float4(s.x * inv, s.y * inv, s.z * inv, g3);
    sw[o] = Wb4[c];
  }
  __syncthreads();

  const int pbase = blockIdx.x * 4096 + tid * 4;
  const float* xb = x + (size_t)b * 3 * HW;
  float4 X0[4], X1[4], X2[4];
#pragma unroll
  for (int pi = 0; pi < 4; ++pi) {
    const int p = pbase + pi * 1024;
    X0[pi] = *reinterpret_cast<const float4*>(xb + p);
    X1[pi] = *reinterpret_cast<const float4*>(xb + HW + p);
    X2[pi] = *reinterpret_cast<const float4*>(xb + 2 * HW + p);
  }
  float* ob = out + (size_t)(b * 256 + c0) * HW;
  for (int ci = 0; ci < 32; ++ci) {
    const float4 g = sg[ci];
    const float4 w = sw[ci];
    float* oc = ob + (size_t)ci * HW + pbase;
#pragma unroll
    for (int pi = 0; pi < 4; ++pi) {
      const float4 A = X0[pi], B = X1[pi], C = X2[pi];
      f32x4 r;
      {
        const float y = fmaf(g.x, A.x, fmaf(g.y, B.x, fmaf(g.z, C.x, g.w)));
        r.x = y * sigmoidf_(y) + fmaf(w.x, A.x, fmaf(w.y, B.x, fmaf(w.z, C.x, w.w)));
      }
      {
        const float y = fmaf(g.x, A.y, fmaf(g.y, B.y, fmaf(g.z, C.y, g.w)));
        r.y = y * sigmoidf_(y) + fmaf(w.x, A.y, fmaf(w.y, B.y, fmaf(w.z, C.y, w.w)));
      }
      {
        const float y = fmaf(g.x, A.z, fmaf(g.y, B.z, fmaf(g.z, C.z, g.w)));
        r.z = y * sigmoidf_(y) + fmaf(w.x, A.z, fmaf(w.y, B.z, fmaf(w.z, C.z, w.w)));
      }
      {
        const float y = fmaf(g.x, A.w, fmaf(g.y, B.w, fmaf(g.z, C.w, g.w)));
        r.w = y * sigmoidf_(y) + fmaf(w.x, A.w, fmaf(w.y, B.w, fmaf(w.z, C.w, w.w)));
      }
      *reinterpret_cast<f32x4*>(oc + pi * 1024) = r;
    }
  }
}

extern "C" void kernel_launch(void* const* d_in, const int* in_sizes, int n_in,
                              void* d_out, int out_size, void* d_ws, size_t ws_size,
                              hipStream_t stream) {
  const float* x     = (const float*)d_in[0];
  const float* Wi    = (const float*)d_in[1];
  const float* bi    = (const float*)d_in[2];
  const float* Wqkv  = (const float*)d_in[3];
  const float* Wo    = (const float*)d_in[4];
  const float* bo    = (const float*)d_in[5];
  const float* Wf    = (const float*)d_in[6];
  const float* bf    = (const float*)d_in[7];
  const float* gamma = (const float*)d_in[8];
  const float* beta  = (const float*)d_in[9];
  const float* rmean = (const float*)d_in[10];
  const float* rvar  = (const float*)d_in[11];

  float* out = (float*)d_out;
  float* att = out + (size_t)NBATCH * 256 * HW;
  float* wsf = (float*)d_ws;

  k_prep<<<dim3(525), dim3(256), 0, stream>>>(x, Wi, bi, Wqkv, Wo, bo, Wf, bf,
                                              wsf + WS_PART, wsf + WS_WFO,
                                              wsf + WS_BFO, wsf + WS_WB4,
                                              wsf + WS_AQ);
  k_solveA<<<dim3(8, NBATCH), dim3(256), 0, stream>>>(wsf + WS_PART, wsf + WS_AQ,
                                                      att, wsf + WS_A4G);
  k_final<<<dim3(4, 8, NBATCH), dim3(256), 0, stream>>>(
      x, wsf + WS_WFO, wsf + WS_BFO, wsf + WS_A4G,
      (const float4*)(wsf + WS_WB4), gamma, beta, rmean, rvar, out);
}